// Round 14
// baseline (3822.848 us; speedup 1.0000x reference)
//
#include <hip/hip_runtime.h>
#include <stdint.h>

// Farthest point sampling, pointops semantics.
// B=8 batches, n=65536, stride=64 -> m=1024 samples/batch.
//
// Round 14 = round 13 (1-wave WGs, zero barriers in loop, packed keys,
// parity cells, dual-domain sc0/sc1) with three step-structure fixes:
//  (1) split-lane poll: lanes 0-31 probe sc0 cells every iter (~250cy);
//      lanes 32-63 probe the sc1 mirrors every 16th iter. Exit when
//      ballot|ballot>>32 covers all 32 slots. No budget/sticky state;
//      sc1 probed infinitely often => deadlock-free.
//  (2) publish straight from the max-owning lane (ballot -> src).
//  (3) no per-iteration memory clobber: LDS coords are written once, so
//      the compiler may promote them to registers (launch_bounds(64,1)
//      gives headroom); otherwise the re-issued reads after publish
//      complete under the poll. Either way LDS latency leaves the
//      critical path.
//
// Correctness: keys are 8B single-copy-atomic, self-contained
// (it|dist_bits|0xFFFF-idx); parity-double-buffered cells, monotone
// tags; round-7 induction: slot s's parity cell for step it is
// overwritten only by publish(it+2) from wave s, which follows wave s's
// poll(it+1), which requires EVERY wave published (it+1), which each
// does only after completing poll(it) in wave program order. Both
// domain copies carry identical payloads; stale keys (tag<it) lose the
// u64 max automatically. comm memset every launch -> replay-determinism.

#define G      32    // workgroups (waves) per batch == slots per batch
#define BS     64    // threads per workgroup = 1 wave
#define PPT    32    // points per thread (G*BS*PPT == n)
#define NC     8     // float4 chunks per thread
#define NBATCH 8

typedef unsigned long long u64;
typedef unsigned int u32;

// key layout: [63:48]=it  [47:16]=float bits of best dist (nonneg)
//             [15:0]=0xFFFF-idx  (bigger wins => smaller idx wins ties,
//             numpy argmax first-max semantics; nonneg IEEE floats
//             compare like their bit patterns)

__device__ inline u64 ld_sc0(const u64* a) {
    u64 v;
    asm volatile("global_load_dwordx2 %0, %1, off sc0\n\t"
                 "s_waitcnt vmcnt(0)"
                 : "=v"(v) : "v"(a));
    return v;
}
__device__ inline void st_sc0(u64* a, u64 v) {
    asm volatile("global_store_dwordx2 %0, %1, off sc0"
                 :: "v"(a), "v"(v));
}

__global__ __launch_bounds__(BS, 1)
void fps_r14(const float* __restrict__ p, int n, int m,
             u64* __restrict__ comm,
             float* __restrict__ out_np, float* __restrict__ out_no,
             float* __restrict__ out_idx)
{
#pragma clang fp contract(off)
    const int bg   = blockIdx.x;
    const int b    = bg & (NBATCH - 1);  // %8: co-XCD under round-robin CP
    const int g    = bg >> 3;            // 0..31 within batch
    const int t    = threadIdx.x;        // == lane
    const int gbase = b * n;
    const int tbase = g * (BS * PPT) + t * PPT;  // batch-local thread base

    __shared__ float4 xs[NC * BS], ys[NC * BS], zs[NC * BS];  // 24 KB

    // ---- stage 32 pts/thread into LDS, float4-transposed (one-time) ----
    {
        const float4* pb = (const float4*)(p + 3ull * (u32)(gbase + tbase));
#pragma unroll
        for (int h = 0; h < 2; ++h) {
            float c[48];
#pragma unroll
            for (int v = 0; v < 12; ++v) {
                float4 f = pb[h * 12 + v];
                c[4 * v + 0] = f.x; c[4 * v + 1] = f.y;
                c[4 * v + 2] = f.z; c[4 * v + 3] = f.w;
            }
#pragma unroll
            for (int cc = 0; cc < 4; ++cc) {
                int ch = h * 4 + cc;
                xs[ch * BS + t] = make_float4(c[(cc * 4 + 0) * 3 + 0],
                                              c[(cc * 4 + 1) * 3 + 0],
                                              c[(cc * 4 + 2) * 3 + 0],
                                              c[(cc * 4 + 3) * 3 + 0]);
                ys[ch * BS + t] = make_float4(c[(cc * 4 + 0) * 3 + 1],
                                              c[(cc * 4 + 1) * 3 + 1],
                                              c[(cc * 4 + 2) * 3 + 1],
                                              c[(cc * 4 + 3) * 3 + 1]);
                zs[ch * BS + t] = make_float4(c[(cc * 4 + 0) * 3 + 2],
                                              c[(cc * 4 + 1) * 3 + 2],
                                              c[(cc * 4 + 2) * 3 + 2],
                                              c[(cc * 4 + 3) * 3 + 2]);
            }
        }
    }
    __syncthreads();   // LDS ready; never written again (promotable reads)

    // coord registers (compiler may keep these live across the whole loop)
    float4 CX[NC], CY[NC], CZ[NC];
#pragma unroll
    for (int cc = 0; cc < NC; ++cc) {
        CX[cc] = xs[cc * BS + t];
        CY[cc] = ys[cc * BS + t];
        CZ[cc] = zs[cc * BS + t];
    }

    float dist[PPT];
#pragma unroll
    for (int j = 0; j < PPT; ++j) dist[j] = 1e10f;

    // first query = point 0 of the batch
    float qx = p[3ull * (u32)gbase + 0];
    float qy = p[3ull * (u32)gbase + 1];
    float qz = p[3ull * (u32)gbase + 2];

    if (g == 0 && t == 0) {
        out_idx[(size_t)b * m] = (float)gbase;
        out_np[(size_t)(b * m) * 3 + 0] = qx;
        out_np[(size_t)(b * m) * 3 + 1] = qy;
        out_np[(size_t)(b * m) * 3 + 2] = qz;
        out_no[b] = (float)((b + 1) * m);
    }

    // per-batch comm (1 KB): sc0 cells [par*32], sc1 cells [64 + par*32]
    u64* cb = comm + (size_t)b * 128;

    for (int it = 1; it < m; ++it) {
        // ---- local distance update + per-thread argmax (ids ascend in j) ----
        float best = -1.0f;
        int   bj   = 0;
#pragma unroll
        for (int cc = 0; cc < NC; ++cc) {
            float xl[4] = {CX[cc].x, CX[cc].y, CX[cc].z, CX[cc].w};
            float yl[4] = {CY[cc].x, CY[cc].y, CY[cc].z, CY[cc].w};
            float zl[4] = {CZ[cc].x, CZ[cc].y, CZ[cc].z, CZ[cc].w};
#pragma unroll
            for (int e = 0; e < 4; ++e) {
                float dx = xl[e] - qx;
                float dy = yl[e] - qy;
                float dz = zl[e] - qz;
                float d  = dx * dx + dy * dy + dz * dz;  // contract off
                int j = cc * 4 + e;
                float nd = fminf(dist[j], d);
                dist[j] = nd;
                if (nd > best) { best = nd; bj = j; }    // strict >: earliest j
            }
        }
        int bidx = tbase + bj;   // batch-local winner idx (ascends with lane)

        // ---- wave argmax: fmax butterfly + first-max lane pick ----
        float v = best;
#pragma unroll
        for (int off = 1; off < 64; off <<= 1)
            v = fmaxf(v, __shfl_xor(v, off));
        u64 msk = __ballot(best == v);
        int src = __ffsll((unsigned long long)msk) - 1;

        u64* sb0 = cb + (size_t)(it & 1) * G;          // sc0 cells (2 lines)
        u64* sb1 = cb + 2 * G + (size_t)(it & 1) * G;  // sc1 mirrors

        // ---- max-owning lane publishes its own candidate (both domains) ----
        if (t == src) {
            u64 kk = ((u64)(u32)it << 48)
                   | ((u64)(u32)__float_as_uint(best) << 16)
                   | (u64)(u32)(0xFFFF - bidx);
            st_sc0(sb0 + g, kk);
            __hip_atomic_store(sb1 + g, kk, __ATOMIC_RELAXED,
                               __HIP_MEMORY_SCOPE_AGENT);
        }

        // ---- re-issue coord loads; they complete under the poll (no-op if
        //      the compiler promoted them to registers) ----
#pragma unroll
        for (int cc = 0; cc < NC; ++cc) {
            CX[cc] = xs[cc * BS + t];
            CY[cc] = ys[cc * BS + t];
            CZ[cc] = zs[cc * BS + t];
        }

        // ---- split-lane poll: lanes 0-31 sc0 every iter, lanes 32-63 sc1
        //      every 16th iter; slot i ok if either watcher saw tag==it ----
        u64 k = 0;
        int  iter = 0;
        bool done;
        do {
            bool ok;
            if (t < G) {
                k  = ld_sc0(sb0 + t);
                ok = ((u32)(k >> 48) == (u32)it);
            } else {
                if ((iter & 15) == 15)
                    k = __hip_atomic_load(sb1 + (t - G), __ATOMIC_RELAXED,
                                          __HIP_MEMORY_SCOPE_AGENT);
                ok = ((u32)(k >> 48) == (u32)it);
            }
            u64 bal = __ballot(ok);
            done = (((bal | (bal >> G)) & 0xFFFFFFFFull) == 0xFFFFFFFFull);
            ++iter;
        } while (!done);

        // ---- key-max butterfly over 64 lanes (stale tags lose) ----
#pragma unroll
        for (int off = 1; off < 64; off <<= 1) {
            u64 k2 = __shfl_xor(k, off);
            if (k2 > k) k = k2;
        }
        int kidx = 0xFFFF - (int)(k & 0xFFFF);

        // winner coords from read-only p (L1/L2-warm; no cache-inv in loop)
        const float* wp = p + 3ull * (u32)(gbase + kidx);
        qx = wp[0]; qy = wp[1]; qz = wp[2];

        if (g == 0 && t == 0) {
            out_idx[(size_t)b * m + it] = (float)(gbase + kidx);
            out_np[(size_t)(b * m + it) * 3 + 0] = qx;
            out_np[(size_t)(b * m + it) * 3 + 1] = qy;
            out_np[(size_t)(b * m + it) * 3 + 2] = qz;
        }
    }
}

extern "C" void kernel_launch(void* const* d_in, const int* in_sizes, int n_in,
                              void* d_out, int out_size, void* d_ws, size_t ws_size,
                              hipStream_t stream) {
    const float* p = (const float*)d_in[0];
    int N = in_sizes[0] / 3;           // 524288
    int B = in_sizes[1];               // 8
    int n = N / B;                     // 65536
    int m = (out_size / B - 1) / 4;    // 1024

    float* out_np  = (float*)d_out;
    float* out_no  = out_np + (size_t)B * m * 3;
    float* out_idx = out_no + B;

    u64* comm = (u64*)d_ws;
    // clear all slot cells (both domains, both parities) every launch
    hipMemsetAsync(d_ws, 0, (size_t)NBATCH * 128 * sizeof(u64), stream);

    fps_r14<<<NBATCH * G, BS, 0, stream>>>(p, n, m, comm,
                                           out_np, out_no, out_idx);
}

// Round 15
// 1996.341 us; speedup vs baseline: 1.9149x; 1.9149x over previous
//
#include <hip/hip_runtime.h>
#include <stdint.h>

// Farthest point sampling, pointops semantics.
// B=8 batches, n=65536, stride=64 -> m=1024 samples/batch.
//
// Round 15 = round 13 (best: 2.15ms) + compute-side-only tweaks:
//  (a) coord ds_reads for the NEXT step are issued BEFORE the poll loop,
//      so their LDS latency completes under the vm-poll (the poll asm's
//      "memory" clobber keeps them there). If the compiler chooses to
//      rematerialize at use instead, behavior reverts exactly to r13.
//  (b) the per-step output writer rotates across waves (g == it&31) --
//      wave 0 was a deterministic straggler doing 6 extra stores/step.
// Poll/publish structure is byte-identical to round 13: 1-wave WGs, zero
// barriers in the loop, dual-domain publish (sc0 + sc1), per-iteration
// dual-probe poll (sc0 fast, sc1 fallback on the SAME iteration --
// guaranteed progress, the r14 lesson), packed self-contained keys,
// parity-double-buffered cells, monotone tags.
//
// Correctness: keys are 8B single-copy-atomic, self-contained
// (it|dist_bits|0xFFFF-idx); round-7 induction: slot s's parity cell for
// step it is overwritten only by publish(it+2) from wave s, which follows
// wave s's poll(it+1), which requires EVERY wave published (it+1), which
// each does only after completing poll(it) in wave program order. Both
// domain copies carry identical payloads; stale tags lose the u64 max.
// comm memset every launch -> graph-replay deterministic.

#define G      32    // workgroups (waves) per batch == slots per batch
#define BS     64    // threads per workgroup = 1 wave
#define PPT    32    // points per thread (G*BS*PPT == n)
#define NC     8     // float4 chunks per thread
#define NBATCH 8

typedef unsigned long long u64;
typedef unsigned int u32;

// key layout: [63:48]=it  [47:16]=float bits of best dist (nonneg)
//             [15:0]=0xFFFF-idx  (bigger wins => smaller idx wins ties,
//             numpy argmax first-max semantics; nonneg IEEE floats
//             compare like their bit patterns)

__device__ inline u64 ld_sc0(const u64* a) {
    u64 v;
    asm volatile("global_load_dwordx2 %0, %1, off sc0\n\t"
                 "s_waitcnt vmcnt(0)"
                 : "=v"(v) : "v"(a) : "memory");
    return v;
}
__device__ inline void st_sc0(u64* a, u64 v) {
    asm volatile("global_store_dwordx2 %0, %1, off sc0"
                 :: "v"(a), "v"(v) : "memory");
}

__global__ __launch_bounds__(BS, 1)
void fps_r15(const float* __restrict__ p, int n, int m,
             u64* __restrict__ comm,
             float* __restrict__ out_np, float* __restrict__ out_no,
             float* __restrict__ out_idx)
{
#pragma clang fp contract(off)
    const int bg   = blockIdx.x;
    const int b    = bg & (NBATCH - 1);  // %8: co-XCD under round-robin CP
    const int g    = bg >> 3;            // 0..31 within batch
    const int t    = threadIdx.x;        // == lane
    const int gbase = b * n;
    const int tbase = g * (BS * PPT) + t * PPT;  // batch-local thread base

    __shared__ float4 xs[NC * BS], ys[NC * BS], zs[NC * BS];  // 24 KB

    // ---- stage 32 pts/thread into LDS, float4-transposed (one-time) ----
    {
        const float4* pb = (const float4*)(p + 3ull * (u32)(gbase + tbase));
#pragma unroll
        for (int h = 0; h < 2; ++h) {
            float c[48];
#pragma unroll
            for (int v = 0; v < 12; ++v) {
                float4 f = pb[h * 12 + v];
                c[4 * v + 0] = f.x; c[4 * v + 1] = f.y;
                c[4 * v + 2] = f.z; c[4 * v + 3] = f.w;
            }
#pragma unroll
            for (int cc = 0; cc < 4; ++cc) {
                int ch = h * 4 + cc;
                xs[ch * BS + t] = make_float4(c[(cc * 4 + 0) * 3 + 0],
                                              c[(cc * 4 + 1) * 3 + 0],
                                              c[(cc * 4 + 2) * 3 + 0],
                                              c[(cc * 4 + 3) * 3 + 0]);
                ys[ch * BS + t] = make_float4(c[(cc * 4 + 0) * 3 + 1],
                                              c[(cc * 4 + 1) * 3 + 1],
                                              c[(cc * 4 + 2) * 3 + 1],
                                              c[(cc * 4 + 3) * 3 + 1]);
                zs[ch * BS + t] = make_float4(c[(cc * 4 + 0) * 3 + 2],
                                              c[(cc * 4 + 1) * 3 + 2],
                                              c[(cc * 4 + 2) * 3 + 2],
                                              c[(cc * 4 + 3) * 3 + 2]);
            }
        }
    }
    __syncthreads();   // LDS ready; never written again

    float dist[PPT];
#pragma unroll
    for (int j = 0; j < PPT; ++j) dist[j] = 1e10f;

    // coord working set for the upcoming step (hoisted loads)
    float4 CX[NC], CY[NC], CZ[NC];
#pragma unroll
    for (int cc = 0; cc < NC; ++cc) {
        CX[cc] = xs[cc * BS + t];
        CY[cc] = ys[cc * BS + t];
        CZ[cc] = zs[cc * BS + t];
    }

    // first query = point 0 of the batch
    float qx = p[3ull * (u32)gbase + 0];
    float qy = p[3ull * (u32)gbase + 1];
    float qz = p[3ull * (u32)gbase + 2];

    if (g == 0 && t == 0) {
        out_idx[(size_t)b * m] = (float)gbase;
        out_np[(size_t)(b * m) * 3 + 0] = qx;
        out_np[(size_t)(b * m) * 3 + 1] = qy;
        out_np[(size_t)(b * m) * 3 + 2] = qz;
        out_no[b] = (float)((b + 1) * m);
    }

    // per-batch comm (1 KB): sc0 cells [par*32], sc1 cells [64 + par*32]
    u64* cb = comm + (size_t)b * 128;

    for (int it = 1; it < m; ++it) {
        // ---- local distance update + per-thread argmax (ids ascend in j) ----
        float best = -1.0f;
        int   bj   = 0;
#pragma unroll
        for (int cc = 0; cc < NC; ++cc) {
            float xl[4] = {CX[cc].x, CX[cc].y, CX[cc].z, CX[cc].w};
            float yl[4] = {CY[cc].x, CY[cc].y, CY[cc].z, CY[cc].w};
            float zl[4] = {CZ[cc].x, CZ[cc].y, CZ[cc].z, CZ[cc].w};
#pragma unroll
            for (int e = 0; e < 4; ++e) {
                float dx = xl[e] - qx;
                float dy = yl[e] - qy;
                float dz = zl[e] - qz;
                float d  = dx * dx + dy * dy + dz * dz;  // contract off
                int j = cc * 4 + e;
                float nd = fminf(dist[j], d);
                dist[j] = nd;
                if (nd > best) { best = nd; bj = j; }    // strict >: earliest j
            }
        }
        int bidx = tbase + bj;   // batch-local winner idx (ascends with lane)

        // ---- ballot wave argmax: max butterfly + first-max lane pick ----
        float v = best;
#pragma unroll
        for (int off = 1; off < 64; off <<= 1)
            v = fmaxf(v, __shfl_xor(v, off));
        u64 msk = __ballot(best == v);
        int src = __ffsll((unsigned long long)msk) - 1;
        int widx = __shfl(bidx, src);    // smallest idx among maxima

        u64* sb0 = cb + (size_t)(it & 1) * G;          // sc0 cells (2 lines)
        u64* sb1 = cb + 2 * G + (size_t)(it & 1) * G;  // sc1 mirrors

        // ---- lane 0: dual publish of this wave's self-contained key ----
        if (t == 0) {
            u64 kk = ((u64)(u32)it << 48)
                   | ((u64)(u32)__float_as_uint(v) << 16)
                   | (u64)(u32)(0xFFFF - widx);
            st_sc0(sb0 + g, kk);
            __hip_atomic_store(sb1 + g, kk, __ATOMIC_RELAXED,
                               __HIP_MEMORY_SCOPE_AGENT);
        }

        // ---- hoisted coord loads for step it+1: lgkm latency completes
        //      under the vm-poll below ("memory"-clobbered asm pins them) ----
#pragma unroll
        for (int cc = 0; cc < NC; ++cc) {
            CX[cc] = xs[cc * BS + t];
            CY[cc] = ys[cc * BS + t];
            CZ[cc] = zs[cc * BS + t];
        }

        // ---- all lanes: dual-probe poll (sc0 fast, sc1 same-iteration
        //      fallback => guaranteed progress; the r14 lesson) ----
        u64 k = 0;
        bool ok;
        do {
            ok = true;
            if (t < G) {
                k = ld_sc0(sb0 + t);
                if ((u32)(k >> 48) != (u32)it) {
                    k = __hip_atomic_load(sb1 + t, __ATOMIC_RELAXED,
                                          __HIP_MEMORY_SCOPE_AGENT);
                }
                ok = ((u32)(k >> 48) == (u32)it);
            } else {
                k = 0;   // upper lanes: never win the key-max
            }
        } while (!__all(ok));

        // ---- key-max butterfly over 64 lanes (upper 32 carry 0) ----
#pragma unroll
        for (int off = 1; off < 64; off <<= 1) {
            u64 k2 = __shfl_xor(k, off);
            if (k2 > k) k = k2;
        }
        int kidx = 0xFFFF - (int)(k & 0xFFFF);

        // winner coords from read-only p (L1/L2-warm; no cache-inv in loop)
        const float* wp = p + 3ull * (u32)(gbase + kidx);
        qx = wp[0]; qy = wp[1]; qz = wp[2];

        // rotated writer: removes the constant wave-0 straggler
        if (g == (it & (G - 1)) && t == 0) {
            out_idx[(size_t)b * m + it] = (float)(gbase + kidx);
            out_np[(size_t)(b * m + it) * 3 + 0] = qx;
            out_np[(size_t)(b * m + it) * 3 + 1] = qy;
            out_np[(size_t)(b * m + it) * 3 + 2] = qz;
        }
    }
}

extern "C" void kernel_launch(void* const* d_in, const int* in_sizes, int n_in,
                              void* d_out, int out_size, void* d_ws, size_t ws_size,
                              hipStream_t stream) {
    const float* p = (const float*)d_in[0];
    int N = in_sizes[0] / 3;           // 524288
    int B = in_sizes[1];               // 8
    int n = N / B;                     // 65536
    int m = (out_size / B - 1) / 4;    // 1024

    float* out_np  = (float*)d_out;
    float* out_no  = out_np + (size_t)B * m * 3;
    float* out_idx = out_no + B;

    u64* comm = (u64*)d_ws;
    // clear all slot cells (both domains, both parities) every launch
    hipMemsetAsync(d_ws, 0, (size_t)NBATCH * 128 * sizeof(u64), stream);

    fps_r15<<<NBATCH * G, BS, 0, stream>>>(p, n, m, comm,
                                           out_np, out_no, out_idx);
}